// Round 10
// baseline (5513.317 us; speedup 1.0000x reference)
//
#include <hip/hip_runtime.h>

#define SS 4096
#define TT 2048

// clang native vector types: usable directly in asm "v" constraints
typedef float v4f __attribute__((ext_vector_type(4)));
typedef float v2f __attribute__((ext_vector_type(2)));
typedef unsigned u2 __attribute__((ext_vector_type(2)));

// ---------- LLC-coherent (agent) memory ops, hand-rolled ----------
// sc0 sc1 => bypass non-coherent per-XCD L2, serve at Infinity Cache.

// two v4f, 8KB apart (thread's two poll slices)
__device__ __forceinline__ void llc_load2(const v4f* p, v4f& a, v4f& b) {
  asm volatile(
      "global_load_dwordx4 %0, %2, off sc0 sc1\n\t"
      "global_load_dwordx4 %1, %3, off sc0 sc1\n\t"
      "s_waitcnt vmcnt(0)"
      : "=&v"(a), "=&v"(b)
      : "v"(p), "v"(p + 512)
      : "memory");
}

__device__ __forceinline__ void llc_load4x4(const v4f* p,
                                            v4f& a, v4f& b, v4f& c, v4f& d) {
  asm volatile(
      "global_load_dwordx4 %0, %4, off sc0 sc1\n\t"
      "global_load_dwordx4 %1, %5, off sc0 sc1\n\t"
      "global_load_dwordx4 %2, %6, off sc0 sc1\n\t"
      "global_load_dwordx4 %3, %7, off sc0 sc1\n\t"
      "s_waitcnt vmcnt(0)"
      : "=&v"(a), "=&v"(b), "=&v"(c), "=&v"(d)
      : "v"(p), "v"(p + 256), "v"(p + 512), "v"(p + 768)
      : "memory");
}

// sentinel poll: word 0 of each 8B chunk (4B x 4). Each producer chunk is
// written by ONE global_store_dwordx2 (8B, single transaction) -> sentinel
// sign flip implies the whole chunk is LLC-visible.
__device__ __forceinline__ void llc_sent4(const float* p0, const float* p1,
                                          const float* p2, const float* p3,
                                          float& a, float& b, float& c, float& d) {
  asm volatile(
      "global_load_dword %0, %4, off sc0 sc1\n\t"
      "global_load_dword %1, %5, off sc0 sc1\n\t"
      "global_load_dword %2, %6, off sc0 sc1\n\t"
      "global_load_dword %3, %7, off sc0 sc1\n\t"
      "s_waitcnt vmcnt(0)"
      : "=&v"(a), "=&v"(b), "=&v"(c), "=&v"(d)
      : "v"(p0), "v"(p1), "v"(p2), "v"(p3)
      : "memory");
}

// store + vmcnt(0): the drain is LOAD-BEARING (round-8 lesson): it forces
// the write to the coherency point promptly; removing it delayed visibility
// and regressed 1.7x.
__device__ __forceinline__ void llc_store2_drain(float* p, v2f v) {
  asm volatile("global_store_dwordx2 %0, %1, off sc0 sc1\n\t"
               "s_waitcnt vmcnt(0)"
               :: "v"(p), "v"(v) : "memory");
}

// straggle side-channel: 64-way LDS bank conflict (all lanes -> bank 0).
// SQ_LDS_BANK_CONFLICT += ~63 per wave execution => counts retry passes.
__device__ __forceinline__ void straggle_tick(int lane) {
  float dummy;
  asm volatile("ds_read_b32 %0, %1\n\t"
               "s_waitcnt lgkmcnt(0)"
               : "=v"(dummy) : "v"(lane << 7) : "memory");
  asm volatile("" :: "v"(dummy));
}

// ---------- helpers ----------

__device__ __forceinline__ unsigned short f2bf_rn(float f) {
  unsigned int u = __float_as_uint(f);
  u += 0x7FFFu + ((u >> 16) & 1u);   // RNE; inputs positive finite
  return (unsigned short)(u >> 16);
}

__device__ __forceinline__ unsigned pkbf(float a, float b) {
  return (unsigned)f2bf_rn(a) | ((unsigned)f2bf_rn(b) << 16);
}

__device__ __forceinline__ float blo(unsigned w) { return __uint_as_float(w << 16); }
__device__ __forceinline__ float bhi(unsigned w) { return __uint_as_float(w & 0xFFFF0000u); }

// 4 MACs: packed-bf16 E pair-of-pairs vs f32 q vector, f32 accumulate
__device__ __forceinline__ v4f fma4(u2 e, v4f q, v4f a) {
  a.x = fmaf(blo(e.x), q.x, a.x);
  a.y = fmaf(bhi(e.x), q.y, a.y);
  a.z = fmaf(blo(e.y), q.z, a.z);
  a.w = fmaf(bhi(e.y), q.w, a.w);
  return a;
}

// OR of (sign-adjusted) words: ready iff top bit of result is 0
__device__ __forceinline__ unsigned orsgn(v4f v, unsigned e) {
  return (__float_as_uint(v.x) ^ e) | (__float_as_uint(v.y) ^ e)
       | (__float_as_uint(v.z) ^ e) | (__float_as_uint(v.w) ^ e);
}

// ---------- persistent forward recursion (r9 protocol + emit prefetch) ----------
// 256 blocks x 512 threads (8 waves), 1 block/CU. Block b owns rows
// [16b,16b+16); wave w owns rows [16b+2w, +2). E in 32 named u2 regs
// (packed bf16, 64 VGPR/lane). Protocol identical to round 9 (4722us,
// verified): poll full-data first (98% one-pass per side-channel),
// sentinel retries, stage raw to LDS double buffer, ONE barrier, GEMV,
// reduce, store WITH drain. Round-10 deltas:
//  (1) EMIT PREFETCH +1 STEP: asm-issued global_load_dwordx2 for
//      emit[t+1] placed AFTER __syncthreads (so the barrier's vmcnt drain
//      can't catch it); consumed at step t+1's store. Removes the cold-HBM
//      emit latency from the poll's vmcnt(0) (r9: poll wait =
//      max(LLC RT, HBM RT)). Loop unrolled x2 (emA/emB) so no reg copy.
//  (2) init_q folded in: each block stores its own q0 slice as "step 0"
//      of the same sign protocol, before the (long) E-init.
// Sign protocol unchanged: stored sign of step t is s_t = ((t>>1)&1)?-1:+1;
// output scale folds s_t*s_{t-1} (+ odd t, - even t); 0xAA poison negative.
#define K16(X) X(0) X(1) X(2) X(3) X(4) X(5) X(6) X(7) \
               X(8) X(9) X(10) X(11) X(12) X(13) X(14) X(15)

__global__ void __launch_bounds__(512, 1) __attribute__((amdgpu_waves_per_eu(2, 2)))
hmm_fwd(const float* __restrict__ lt, const float* __restrict__ m0,
        const float* __restrict__ emit, float* q, float* out) {
  __shared__ float qs[2][SS];              // 32 KiB (double buffer)
  __shared__ float wsum[4];
  const int b    = blockIdx.x;
  const int tid  = threadIdx.x;
  const int wave = tid >> 6;
  const int lane = tid & 63;
  const int row0 = (b << 4) + (wave << 1);   // 2 rows per wave

  // ---- "step 0": publish own q0 slice FIRST (consumers poll it at t=1) ----
  {
    v2f m0v = *(const v2f*)(m0 + row0);
    v2f e0v = *(const v2f*)(emit + row0);
    v2f q0;
    q0.x = __expf(m0v.x + e0v.x);            // positive = stored sign s_0
    q0.y = __expf(m0v.y + e0v.y);
    if (lane == 0) llc_store2_drain(q + row0, q0);
  }

  // emit[1] prefetch flies during the E-init below
  v2f emA, emB;
  asm volatile("global_load_dwordx2 %0, %1, off"
               : "=&v"(emA) : "v"(emit + (size_t)SS + row0) : "memory");

  // 32 named packed-bf16 E registers:
  // e{r}_{k} = bf16(exp(log_trans[row0+r][k*256+4l .. +4])), 2x2 packed
#define DECL_E(k) u2 e0_##k, e1_##k;
  K16(DECL_E)
#undef DECL_E

  {
    const float* s0 = lt + (size_t)row0 * SS + (lane << 2);
    const float* s1 = s0 + SS;
#define INIT_E(k) { \
    v4f t0 = *(const v4f*)(s0 + ((k) << 8)); \
    v4f t1 = *(const v4f*)(s1 + ((k) << 8)); \
    e0_##k = (u2){pkbf(__expf(t0.x), __expf(t0.y)), pkbf(__expf(t0.z), __expf(t0.w))}; \
    e1_##k = (u2){pkbf(__expf(t1.x), __expf(t1.y)), pkbf(__expf(t1.z), __expf(t1.w))}; }
    K16(INIT_E)
#undef INIT_E
  }

#define FMA_K(k) { \
    v4f qv = qv4[((k) << 6) + lane]; \
    a0 = fma4(e0_##k, qv, a0);  a1 = fma4(e1_##k, qv, a1); }

#define STEP(T, EMC, EMN) { \
    const unsigned e = (unsigned)(((unsigned)((T) - 1) >> 1) & 1) << 31; \
    { \
      const v4f* qsrc4 = (const v4f*)(q + (((T) - 1) & 1) * SS); \
      v4f va, vb; \
      llc_load2(qsrc4 + tid, va, vb); \
      unsigned o = orsgn(va, e) | orsgn(vb, e); \
      if (o >> 31) { \
        const float* qw = (const float*)qsrc4; \
        const float* p0 = qw + (tid << 2); \
        const float* p1 = p0 + 2; \
        const float* p2 = p0 + 2048; \
        const float* p3 = p0 + 2050; \
        for (;;) { \
          straggle_tick(lane);   /* side-channel: count this pass */ \
          float s0v, s1v, s2v, s3v; \
          llc_sent4(p0, p1, p2, p3, s0v, s1v, s2v, s3v); \
          unsigned so = (__float_as_uint(s0v) ^ e) | (__float_as_uint(s1v) ^ e) \
                      | (__float_as_uint(s2v) ^ e) | (__float_as_uint(s3v) ^ e); \
          if (!(so >> 31)) break; \
        } \
        llc_load2(qsrc4 + tid, va, vb); \
      } \
      v4f* qsb = (v4f*)qs[(T) & 1]; \
      qsb[tid]       = va; \
      qsb[tid + 512] = vb; \
    } \
    __syncthreads();   /* single barrier per step (double-buffered qs) */ \
    if ((T) < TT) { \
      asm volatile("global_load_dwordx2 %0, %1, off" \
                   : "=&v"(EMN) \
                   : "v"(emit + (size_t)((T) + 1) * SS + row0) : "memory"); \
    } \
    v4f a0 = {0.f, 0.f, 0.f, 0.f}, a1 = a0; \
    const v4f* qv4 = (const v4f*)qs[(T) & 1]; \
    K16(FMA_K) \
    float scale = (((T) & 255) == 0) ? 0x1p-46f : 1.0f;  /* exact pow2 renorm */ \
    if (!((T) & 1)) scale = -scale;                       /* s_t * s_{t-1} */ \
    v2f ex;   /* EMC prefetched last step, drained by this step's poll */ \
    ex.x = __expf(EMC.x) * scale; \
    ex.y = __expf(EMC.y) * scale; \
    float acc0 = (a0.x + a0.y) + (a0.z + a0.w); \
    float acc1 = (a1.x + a1.y) + (a1.z + a1.w); \
    _Pragma("unroll") \
    for (int m = 32; m > 0; m >>= 1) { \
      acc0 += __shfl_xor(acc0, m); \
      acc1 += __shfl_xor(acc1, m); \
    } \
    v2f r; \
    r.x = acc0 * ex.x; \
    r.y = acc1 * ex.y; \
    if (lane == 0) llc_store2_drain(q + ((T) & 1) * SS + row0, r); \
  }

  for (int t = 1; t <= TT; t += 2) {
    STEP(t,     emA, emB)
    STEP(t + 1, emB, emA)
  }
#undef STEP
#undef FMA_K

  // final reduction: q_T (t=2048) in buffer 0, stored sign positive
  if (b == 0) {
    if (tid < 256) {
      const v4f* qf4 = (const v4f*)q;
      v4f va, vb, vc, vd;
      for (;;) {
        llc_load4x4(qf4 + tid, va, vb, vc, vd);
        unsigned o = orsgn(va, 0) | orsgn(vb, 0) | orsgn(vc, 0) | orsgn(vd, 0);
        if (!(o >> 31)) break;
      }
      float s = va.x + va.y + va.z + va.w + vb.x + vb.y + vb.z + vb.w
              + vc.x + vc.y + vc.z + vc.w + vd.x + vd.y + vd.z + vd.w;
#pragma unroll
      for (int m = 32; m > 0; m >>= 1) s += __shfl_xor(s, m);
      if (lane == 0) wsum[wave] = s;
    }
    __syncthreads();
    if (tid == 0) {
      float tot = wsum[0] + wsum[1] + wsum[2] + wsum[3];
      out[0] = logf(tot) + 368.0f * 0.693147180559945f;   // 8 rescales * 46 * ln2
    }
  }
}

// ---------- launch ----------
extern "C" void kernel_launch(void* const* d_in, const int* in_sizes, int n_in,
                              void* d_out, int out_size, void* d_ws, size_t ws_size,
                              hipStream_t stream) {
  const float* log_M0    = (const float*)d_in[0];
  const float* log_trans = (const float*)d_in[1];
  const float* log_emit  = (const float*)d_in[2];
  // d_in[3] = T (fixed 2048, unused)

  float* q   = (float*)d_ws;     // 2 x 16 KiB (poisoned 0xAA = negative)
  float* out = (float*)d_out;

  hipLaunchKernelGGL(hmm_fwd, dim3(256), dim3(512), 0, stream,
                     log_trans, log_M0, log_emit, q, out);
}

// Round 11
// 4587.826 us; speedup vs baseline: 1.2017x; 1.2017x over previous
//
#include <hip/hip_runtime.h>

#define SS 4096
#define TT 2048

// clang native vector types: usable directly in asm "v" constraints
typedef float v4f __attribute__((ext_vector_type(4)));
typedef float v2f __attribute__((ext_vector_type(2)));

// ---------- LLC-coherent (agent) memory ops, hand-rolled ----------
// sc0 sc1 => bypass non-coherent per-XCD L2, serve at Infinity Cache.

// two v4f, 8KB apart (thread's two poll slices)
__device__ __forceinline__ void llc_load2(const v4f* p, v4f& a, v4f& b) {
  asm volatile(
      "global_load_dwordx4 %0, %2, off sc0 sc1\n\t"
      "global_load_dwordx4 %1, %3, off sc0 sc1\n\t"
      "s_waitcnt vmcnt(0)"
      : "=&v"(a), "=&v"(b)
      : "v"(p), "v"(p + 512)
      : "memory");
}

__device__ __forceinline__ void llc_load4x4(const v4f* p,
                                            v4f& a, v4f& b, v4f& c, v4f& d) {
  asm volatile(
      "global_load_dwordx4 %0, %4, off sc0 sc1\n\t"
      "global_load_dwordx4 %1, %5, off sc0 sc1\n\t"
      "global_load_dwordx4 %2, %6, off sc0 sc1\n\t"
      "global_load_dwordx4 %3, %7, off sc0 sc1\n\t"
      "s_waitcnt vmcnt(0)"
      : "=&v"(a), "=&v"(b), "=&v"(c), "=&v"(d)
      : "v"(p), "v"(p + 256), "v"(p + 512), "v"(p + 768)
      : "memory");
}

// sentinel poll: word 0 of each 8B chunk (4B x 4). Each producer chunk is
// written by ONE global_store_dwordx2 (8B, single transaction) -> sentinel
// sign flip implies the whole chunk is LLC-visible.
__device__ __forceinline__ void llc_sent4(const float* p0, const float* p1,
                                          const float* p2, const float* p3,
                                          float& a, float& b, float& c, float& d) {
  asm volatile(
      "global_load_dword %0, %4, off sc0 sc1\n\t"
      "global_load_dword %1, %5, off sc0 sc1\n\t"
      "global_load_dword %2, %6, off sc0 sc1\n\t"
      "global_load_dword %3, %7, off sc0 sc1\n\t"
      "s_waitcnt vmcnt(0)"
      : "=&v"(a), "=&v"(b), "=&v"(c), "=&v"(d)
      : "v"(p0), "v"(p1), "v"(p2), "v"(p3)
      : "memory");
}

// store + vmcnt(0): the drain is LOAD-BEARING (round-8 lesson): it forces
// the write to the coherency point promptly; removing it delayed visibility
// and regressed 1.7x.
__device__ __forceinline__ void llc_store2_drain(float* p, v2f v) {
  asm volatile("global_store_dwordx2 %0, %1, off sc0 sc1\n\t"
               "s_waitcnt vmcnt(0)"
               :: "v"(p), "v"(v) : "memory");
}

// straggle side-channel: LDS bank conflict burst (active lanes -> bank 0).
// SQ_LDS_BANK_CONFLICT increments per retry pass => retry counter.
__device__ __forceinline__ void straggle_tick(int lane) {
  float dummy;
  asm volatile("ds_read_b32 %0, %1\n\t"
               "s_waitcnt lgkmcnt(0)"
               : "=v"(dummy) : "v"(lane << 7) : "memory");
  asm volatile("" :: "v"(dummy));
}

// OR of (sign-adjusted) words: ready iff top bit of result is 0
__device__ __forceinline__ unsigned orsgn(v4f v, unsigned e) {
  return (__float_as_uint(v.x) ^ e) | (__float_as_uint(v.y) ^ e)
       | (__float_as_uint(v.z) ^ e) | (__float_as_uint(v.w) ^ e);
}

// ---------- persistent forward recursion: TRANSPOSED GEMV ----------
// 256 blocks x 512 threads (8 waves), 1 block/CU, waves_per_eu(2,2).
// Round-10 lesson: the step is SELF-CLOCKED by the poll->store chain;
// polling earlier than producer visibility costs a retry quantum. So this
// round shortens the path AFTER the poll instead:
// TRANSPOSE: thread tid polls q cols [4t,4t+4) and [4t+2048,+4) (r9's
// slices) and computes, for ALL 16 block rows, the partial dot over ITS OWN
// 8 columns -- q never touches LDS; the pre-GEMV stage+barrier vanish.
// E lives in 32 named f32 v4f regs (128 VGPR; no bf16 unpacks, GEMV VALU
// halves vs r9). Per-lane row-partials h0..h15 reduce via reduce-scatter
// butterfly (masks 32,16,8,4 keep/send selects; then 2,1): after it, lane
// 4r holds row r summed over the wave. 16 writer lanes -> 1KB padded LDS
// partials [8 waves][17], ONE barrier, wave w combines 8 partials for its
// rows 2w,2w+1, lane 0 applies exp(emit)*scale and stores 8B with drain.
// Poll code, sentinel retry, sign protocol: byte-identical to r9 (4722us).
// Emit load stays INSIDE the poll drain (r9 placement; r10 proved moving
// it earlier makes polls arrive before visibility -> retry storm).
// Sign protocol: stored sign of step t is s_t = ((t>>1)&1)?-1:+1; output
// scale folds s_t*s_{t-1} (+ odd t, - even t); 0xAA poison negative.
#define K16(X) X(0) X(1) X(2) X(3) X(4) X(5) X(6) X(7) \
               X(8) X(9) X(10) X(11) X(12) X(13) X(14) X(15)

__global__ void __launch_bounds__(512, 1) __attribute__((amdgpu_waves_per_eu(2, 2)))
hmm_fwd(const float* __restrict__ lt, const float* __restrict__ lm0,
        const float* __restrict__ emit, float* q, float* out) {
  __shared__ float part[2][8 * 17];        // padded partials, double-buffered
  __shared__ float wsum[4];
  const int b    = blockIdx.x;
  const int tid  = threadIdx.x;
  const int wave = tid >> 6;
  const int lane = tid & 63;
  const int row0 = (b << 4) + (wave << 1);   // this wave's 2 global rows

  // ---- "step 0": publish own q0 slice FIRST (consumers poll it at t=1) ----
  {
    v2f m0v = *(const v2f*)(lm0 + row0);
    v2f e0v = *(const v2f*)(emit + row0);
    v2f q0;
    q0.x = __expf(m0v.x + e0v.x);            // positive = stored sign s_0
    q0.y = __expf(m0v.y + e0v.y);
    if (lane == 0) llc_store2_drain(q + row0, q0);
  }

  // 32 named f32 E registers: eA_r = exp(lt[16b+r][4*tid .. +4]),
  //                           eB_r = exp(lt[16b+r][4*tid+2048 .. +4])
#define DECL_E(r) v4f eA_##r, eB_##r;
  K16(DECL_E)
#undef DECL_E
  {
    const float* baseE = lt + ((size_t)(b << 4)) * SS + (tid << 2);
#define INIT_E(r) { \
    v4f tA = *(const v4f*)(baseE + (size_t)(r) * SS); \
    v4f tB = *(const v4f*)(baseE + (size_t)(r) * SS + 2048); \
    eA_##r = (v4f){__expf(tA.x), __expf(tA.y), __expf(tA.z), __expf(tA.w)}; \
    eB_##r = (v4f){__expf(tB.x), __expf(tB.y), __expf(tB.z), __expf(tB.w)}; }
    K16(INIT_E)
#undef INIT_E
  }

  for (int t = 1; t <= TT; ++t) {
    // emit load: issued right before the poll, drained BY the poll (r9
    // placement — its latency doubles as the poll grace period)
    v2f em;
    if (lane == 0) em = *(const v2f*)(emit + (size_t)t * SS + row0);

    // poll own q slices: expected stored-sign of step t-1 (r9-identical)
    const unsigned e = (unsigned)(((t - 1) >> 1) & 1) << 31;
    const v4f* qsrc4 = (const v4f*)(q + ((t - 1) & 1) * SS);
    v4f va, vb;
    llc_load2(qsrc4 + tid, va, vb);
    {
      unsigned o = orsgn(va, e) | orsgn(vb, e);
      if (o >> 31) {
        const float* qw = (const float*)qsrc4;
        const float* p0 = qw + (tid << 2);
        const float* p1 = p0 + 2;
        const float* p2 = p0 + 2048;
        const float* p3 = p0 + 2050;
        for (;;) {
          straggle_tick(lane);   // side-channel: count this pass
          float s0v, s1v, s2v, s3v;
          llc_sent4(p0, p1, p2, p3, s0v, s1v, s2v, s3v);
          unsigned so = (__float_as_uint(s0v) ^ e) | (__float_as_uint(s1v) ^ e)
                      | (__float_as_uint(s2v) ^ e) | (__float_as_uint(s3v) ^ e);
          if (!(so >> 31)) break;
        }
        llc_load2(qsrc4 + tid, va, vb);   // data now LLC-resident
      }
    }

    // transposed GEMV straight from registers: 16 row-partials over own 8 cols
#define DECL_H(r) float h##r;
    K16(DECL_H)
#undef DECL_H
#define GEMV_R(r) { \
    v4f p = eA_##r * va + eB_##r * vb; \
    h##r = (p.x + p.y) + (p.z + p.w); }
    K16(GEMV_R)
#undef GEMV_R

    // reduce-scatter butterfly: after masks {32,16,8,4}, lane 4r holds row r
    // summed over this wave's 64 lanes; masks {2,1} broadcast within quads.
    const bool b5 = (lane & 32) != 0;
    const bool b4 = (lane & 16) != 0;
    const bool b3 = (lane & 8) != 0;
    const bool b2 = (lane & 4) != 0;
    float n0, n1, n2, n3, n4, n5, n6, n7;
#define RS32(i, A, B) { \
    float kk = b5 ? (B) : (A); \
    float ss = b5 ? (A) : (B); \
    n##i = kk + __shfl_xor(ss, 32); }
    RS32(0, h0, h8)  RS32(1, h1, h9)  RS32(2, h2, h10) RS32(3, h3, h11)
    RS32(4, h4, h12) RS32(5, h5, h13) RS32(6, h6, h14) RS32(7, h7, h15)
#undef RS32
    float mm0, mm1, mm2, mm3;
#define RS16(i, A, B) { \
    float kk = b4 ? (B) : (A); \
    float ss = b4 ? (A) : (B); \
    mm##i = kk + __shfl_xor(ss, 16); }
    RS16(0, n0, n4) RS16(1, n1, n5) RS16(2, n2, n6) RS16(3, n3, n7)
#undef RS16
    float pp0, pp1;
#define RS8(i, A, B) { \
    float kk = b3 ? (B) : (A); \
    float ss = b3 ? (A) : (B); \
    pp##i = kk + __shfl_xor(ss, 8); }
    RS8(0, mm0, mm2) RS8(1, mm1, mm3)
#undef RS8
    float s = (b2 ? pp1 : pp0) + __shfl_xor(b2 ? pp0 : pp1, 4);
    s += __shfl_xor(s, 2);
    s += __shfl_xor(s, 1);

    // 16 writer lanes (lane = 4r) publish wave-partial for local row r
    if (!(lane & 3)) part[t & 1][wave * 17 + (lane >> 2)] = s;
    __syncthreads();   // single barrier per step (partials double-buffered)

    // wave w combines 8 wave-partials for its rows 2w, 2w+1
    const float* pb = part[t & 1];
    float x = pb[(lane & 7) * 17 + (wave << 1) + ((lane >> 3) & 1)];
    x += __shfl_xor(x, 1);
    x += __shfl_xor(x, 2);
    x += __shfl_xor(x, 4);          // lanes 0-7: S(2w); lanes 8-15: S(2w+1)
    float y = __shfl_xor(x, 8);     // lane 0 receives S(2w+1)

    if (lane == 0) {
      float scale = ((t & 255) == 0) ? 0x1p-46f : 1.0f;  // exact pow2 renorm
      if (!(t & 1)) scale = -scale;                       // s_t * s_{t-1}
      v2f r;
      r.x = x * (__expf(em.x) * scale);
      r.y = y * (__expf(em.y) * scale);
      llc_store2_drain(q + (t & 1) * SS + row0, r);
    }
  }

  // final reduction: q_T (t=2048) in buffer 0, stored sign positive
  if (b == 0) {
    if (tid < 256) {
      const v4f* qf4 = (const v4f*)q;
      v4f va, vb, vc, vd;
      for (;;) {
        llc_load4x4(qf4 + tid, va, vb, vc, vd);
        unsigned o = orsgn(va, 0) | orsgn(vb, 0) | orsgn(vc, 0) | orsgn(vd, 0);
        if (!(o >> 31)) break;
      }
      float s = va.x + va.y + va.z + va.w + vb.x + vb.y + vb.z + vb.w
              + vc.x + vc.y + vc.z + vc.w + vd.x + vd.y + vd.z + vd.w;
#pragma unroll
      for (int m = 32; m > 0; m >>= 1) s += __shfl_xor(s, m);
      if (lane == 0) wsum[wave] = s;
    }
    __syncthreads();
    if (tid == 0) {
      float tot = wsum[0] + wsum[1] + wsum[2] + wsum[3];
      out[0] = logf(tot) + 368.0f * 0.693147180559945f;   // 8 rescales * 46 * ln2
    }
  }
}

// ---------- launch ----------
extern "C" void kernel_launch(void* const* d_in, const int* in_sizes, int n_in,
                              void* d_out, int out_size, void* d_ws, size_t ws_size,
                              hipStream_t stream) {
  const float* log_M0    = (const float*)d_in[0];
  const float* log_trans = (const float*)d_in[1];
  const float* log_emit  = (const float*)d_in[2];
  // d_in[3] = T (fixed 2048, unused)

  float* q   = (float*)d_ws;     // 2 x 16 KiB (poisoned 0xAA = negative)
  float* out = (float*)d_out;

  hipLaunchKernelGGL(hmm_fwd, dim3(256), dim3(512), 0, stream,
                     log_trans, log_M0, log_emit, q, out);
}